// Round 2
// baseline (6042.071 us; speedup 1.0000x reference)
//
#include <hip/hip_runtime.h>
#include <hip/hip_bf16.h>
#include <math.h>

#define NN   32768
#define BG   32
#define NPG  1024
#define HD   64
#define KK   24          // neighbors
#define KT   8           // k-slice tile in knn kernel

#define FLTMAX 3.402823466e38f

__device__ __forceinline__ float elu1(float x) { return x > 0.f ? x : expm1f(x); }

// ---------------- input MLP: h = elu(elu(x@W1+b1)@W2+b2) ----------------
__global__ void __launch_bounds__(256) k_mlp_in(
    const float* __restrict__ x, const float* __restrict__ W1, const float* __restrict__ b1,
    const float* __restrict__ W2, const float* __restrict__ b2, float* __restrict__ F) {
  __shared__ float sW1[8*64];
  __shared__ float sW2[64*64];
  __shared__ float sb1[64];
  __shared__ float sb2[64];
  int t = threadIdx.x;
  for (int i = t; i < 8*64; i += 256) sW1[i] = W1[i];
  for (int i = t; i < 64*64; i += 256) sW2[i] = W2[i];
  if (t < 64) { sb1[t] = b1[t]; sb2[t] = b2[t]; }
  __syncthreads();
  int node = blockIdx.x*256 + t;
  float xr[8];
#pragma unroll
  for (int i = 0; i < 8; ++i) xr[i] = x[node*8 + i];
  float h1[64];
#pragma unroll 8
  for (int k = 0; k < 64; ++k) {
    float a = sb1[k];
#pragma unroll
    for (int i = 0; i < 8; ++i) a += xr[i]*sW1[i*64+k];
    h1[k] = elu1(a);
  }
#pragma unroll 2
  for (int d = 0; d < 64; ++d) {
    float a = sb2[d];
#pragma unroll
    for (int k = 0; k < 64; ++k) a += h1[k]*sW2[k*64+d];
    F[node*64 + d] = elu1(a);
  }
}

// ---------------- per-layer: U = X@(A-B)+bc, V = X@B, SQ = rowsum(X^2) ----------------
__global__ void __launch_bounds__(256) k_uv(
    const float* __restrict__ X, const float* __restrict__ Wc, const float* __restrict__ bc,
    float* __restrict__ U, float* __restrict__ V, float* __restrict__ SQ) {
  __shared__ float sA[64*64];
  __shared__ float sB[64*64];
  __shared__ float sbc[64];
  int t = threadIdx.x;
  for (int i = t; i < 64*64; i += 256) { sA[i] = Wc[i]; sB[i] = Wc[64*64 + i]; }
  if (t < 64) sbc[t] = bc[t];
  __syncthreads();
  int node = blockIdx.x*256 + t;
  float xr[64];
  float sq = 0.f;
#pragma unroll
  for (int k = 0; k < 64; ++k) { float v = X[node*64+k]; xr[k] = v; sq += v*v; }
  SQ[node] = sq;
#pragma unroll 2
  for (int d = 0; d < 64; ++d) {
    float ua = 0.f, vb = 0.f;
#pragma unroll
    for (int k = 0; k < 64; ++k) { ua += xr[k]*sA[k*64+d]; vb += xr[k]*sB[k*64+d]; }
    U[node*64+d] = ua - vb + sbc[d];
    V[node*64+d] = vb;
  }
}

// ---------------- helpers for knn selection ----------------
// Ascending bitonic sort of 64 (value, col) pairs, one pair per lane, R rows interleaved.
// Lexicographic order: (value, col).
template<int R>
__device__ __forceinline__ void bitonic64(float (&kv)[R], int (&kc)[R], int lane) {
#pragma unroll
  for (int k = 2; k <= 64; k <<= 1) {
#pragma unroll
    for (int j = k >> 1; j > 0; j >>= 1) {
      bool keepmin = ((lane < (lane ^ j)) == ((lane & k) == 0));
#pragma unroll
      for (int r = 0; r < R; ++r) {
        float ov = __shfl_xor(kv[r], j);
        int   oc = __shfl_xor(kc[r], j);
        bool less = (ov < kv[r]) || (ov == kv[r] && oc < kc[r]);
        bool take = keepmin ? less : !less;
        if (take) { kv[r] = ov; kc[r] = oc; }
      }
    }
  }
}

// Exact fallback: 24x masked argmin extraction (only for pathological tie storms).
__device__ __noinline__ void fallback_row(const float* vr, int lane, int gbase,
                                          long long outbase, int* __restrict__ IDX) {
  unsigned selm = 0;
  for (int it = 0; it < KK; ++it) {
    float bv = FLTMAX; int bj = 0x7fffffff;
#pragma unroll
    for (int m = 0; m < 16; ++m) {
      float vv = ((selm >> m) & 1) ? FLTMAX : vr[m];
      int col = lane + (m << 6);
      bool b = vv < bv; bv = b ? vv : bv; bj = b ? col : bj;
    }
#pragma unroll
    for (int s = 32; s; s >>= 1) {
      float ov = __shfl_xor(bv, s); int oj = __shfl_xor(bj, s);
      bool b = (ov < bv) || (ov == bv && oj < bj);
      bv = b ? ov : bv; bj = b ? oj : bj;
    }
    if (lane == (bj & 63)) selm |= 1u << (bj >> 6);
    if (lane == 0) IDX[outbase + it] = gbase + bj;
  }
}

// ---------------- knn: fused Gram + exact top-24 by (dist, idx) ----------------
// Block = 256 threads (4 waves), 16 rows of one graph (wave w -> rows 4w..4w+3).
// Lane l owns candidate columns {l + 64*m}, m = 0..15; distances live in registers.
__global__ void __launch_bounds__(256) k_knn(
    const float* __restrict__ X, const float* __restrict__ SQ, int* __restrict__ IDX) {
  __shared__ float sKC[KT][NPG];               // 32 KB k-slice of all 1024 columns
  __shared__ float sRow[16][64];               // 4 KB row features
  __shared__ float sRowSq[16];
  __shared__ unsigned long long sCmp[4][4][64]; // 8 KB compacted (dist,col) per wave,row
  int g = blockIdx.x >> 6;
  int rowBase = (blockIdx.x & 63) * 16;
  int gbase = g * NPG;
  int t = threadIdx.x;
  for (int i = t; i < 16*64; i += 256)
    sRow[i>>6][i&63] = X[(size_t)(gbase + rowBase + (i>>6))*64 + (i&63)];
  if (t < 16) sRowSq[t] = SQ[gbase + rowBase + t];
  int wave = t >> 6, lane = t & 63;

  float v[4][16];
#pragma unroll
  for (int r = 0; r < 4; ++r)
#pragma unroll
    for (int m = 0; m < 16; ++m) v[r][m] = 0.f;

  for (int kt = 0; kt < 64/KT; ++kt) {
    __syncthreads();
#pragma unroll
    for (int i = 0; i < 4; ++i) {
      int c = t + 256*i;
      const float* src = X + (size_t)(gbase + c)*64 + kt*KT;
#pragma unroll
      for (int q = 0; q < KT/4; ++q) {
        float4 f4 = *reinterpret_cast<const float4*>(src + q*4);
        sKC[q*4+0][c] = f4.x; sKC[q*4+1][c] = f4.y; sKC[q*4+2][c] = f4.z; sKC[q*4+3][c] = f4.w;
      }
    }
    __syncthreads();
#pragma unroll
    for (int kk = 0; kk < KT; ++kk) {
      int k = kt*KT + kk;
      float xr0 = sRow[wave*4+0][k];
      float xr1 = sRow[wave*4+1][k];
      float xr2 = sRow[wave*4+2][k];
      float xr3 = sRow[wave*4+3][k];
#pragma unroll
      for (int m = 0; m < 16; ++m) {
        float xc = sKC[kk][lane + (m<<6)];
        v[0][m] += xr0*xc;
        v[1][m] += xr1*xc;
        v[2][m] += xr2*xc;
        v[3][m] += xr3*xc;
      }
    }
  }

  // distances: v = rsq + csq - 2*dot  (in place)
  float csq[16];
#pragma unroll
  for (int m = 0; m < 16; ++m) csq[m] = SQ[gbase + lane + (m<<6)];
#pragma unroll
  for (int r = 0; r < 4; ++r) {
    float rsq = sRowSq[wave*4 + r];
#pragma unroll
    for (int m = 0; m < 16; ++m) v[r][m] = rsq + csq[m] - 2.f*v[r][m];
  }

  // phase 2: per-lane argmin per row
  float lm[4]; int lc[4];
#pragma unroll
  for (int r = 0; r < 4; ++r) {
    float bm = v[r][0]; int bc = lane;
#pragma unroll
    for (int m = 1; m < 16; ++m) {
      float vv = v[r][m]; int cc = lane + (m<<6);
      bool b = vv < bm; bm = b ? vv : bm; bc = b ? cc : bc;
    }
    lm[r] = bm; lc[r] = bc;
  }

  // phase 3: sort lane-minima; t = 24th smallest lane-min (valid threshold: >=24 values <= t)
  bitonic64<4>(lm, lc, lane);
  float thr[4];
#pragma unroll
  for (int r = 0; r < 4; ++r) thr[r] = __shfl(lm[r], 23);

  // phase 4: flag, prefix-scan, compact to LDS
  int total[4], excl[4]; unsigned fbits[4];
#pragma unroll
  for (int r = 0; r < 4; ++r) {
    unsigned bits = 0; int cnt = 0;
#pragma unroll
    for (int m = 0; m < 16; ++m) {
      bool f = v[r][m] <= thr[r];
      bits |= ((unsigned)f) << m; cnt += f;
    }
    int pre = cnt;
#pragma unroll
    for (int s = 1; s < 64; s <<= 1) { int o = __shfl_up(pre, s); if (lane >= s) pre += o; }
    total[r] = __shfl(pre, 63);
    excl[r] = pre - cnt; fbits[r] = bits;
  }
#pragma unroll
  for (int r = 0; r < 4; ++r) {
    int slot = excl[r];
#pragma unroll
    for (int m = 0; m < 16; ++m) {
      if ((fbits[r] >> m) & 1) {
        if (slot < 64)
          sCmp[wave][r][slot] =
            ((unsigned long long)__float_as_uint(v[r][m]) << 32) | (unsigned)(lane + (m<<6));
        ++slot;
      }
    }
  }
  __syncthreads();

  // phase 5/6: sort compacted candidates, emit top-24
  bool allfast = total[0] <= 64 && total[1] <= 64 && total[2] <= 64 && total[3] <= 64;
  long long ob0 = (long long)(gbase + rowBase + wave*4) * KK;
  if (allfast) {
    float sv[4]; int sc[4];
#pragma unroll
    for (int r = 0; r < 4; ++r) {
      bool in = lane < total[r];
      unsigned long long kp = in ? sCmp[wave][r][lane] : 0ull;
      sv[r] = in ? __uint_as_float((unsigned)(kp >> 32)) : FLTMAX;
      sc[r] = in ? (int)(unsigned)kp : 0x7fffffff;
    }
    bitonic64<4>(sv, sc, lane);
#pragma unroll
    for (int r = 0; r < 4; ++r)
      if (lane < KK) IDX[ob0 + (long long)r*KK + lane] = gbase + sc[r];
  } else {
    for (int r = 0; r < 4; ++r) {
      if (total[r] <= 64) {
        float sv[1]; int sc[1];
        bool in = lane < total[r];
        unsigned long long kp = in ? sCmp[wave][r][lane] : 0ull;
        sv[0] = in ? __uint_as_float((unsigned)(kp >> 32)) : FLTMAX;
        sc[0] = in ? (int)(unsigned)kp : 0x7fffffff;
        bitonic64<1>(sv, sc, lane);
        if (lane < KK) IDX[ob0 + (long long)r*KK + lane] = gbase + sc[0];
      } else {
        fallback_row(v[r], lane, gbase, ob0 + (long long)r*KK, IDX);
      }
    }
  }
}

// ---------------- aggregate: Fn = X + elu(U + max_j V[j]) ----------------
__global__ void __launch_bounds__(256) k_agg(
    const float* __restrict__ X, const float* __restrict__ U, const float* __restrict__ V,
    const int* __restrict__ IDX, float* __restrict__ Fn) {
  int tid = blockIdx.x*256 + threadIdx.x;
  int node = tid >> 6;
  int lane = tid & 63;
  const int* idx = IDX + (size_t)node*KK;
  float m = -FLTMAX;
#pragma unroll
  for (int t = 0; t < KK; ++t) {
    int j = idx[t];                          // wave-uniform
    m = fmaxf(m, V[(size_t)j*64 + lane]);
  }
  float s = U[(size_t)node*64 + lane] + m;
  Fn[(size_t)node*64 + lane] = X[(size_t)node*64 + lane] + elu1(s);
}

// ---------------- output MLP + batch passthrough ----------------
__global__ void __launch_bounds__(256) k_out(
    const float* __restrict__ F, const float* __restrict__ Wo1, const float* __restrict__ bo1,
    const float* __restrict__ Wo2, const float* __restrict__ bo2,
    const float* __restrict__ Wo3, const float* __restrict__ bo3,
    const int* __restrict__ batch, float* __restrict__ out, int out_size) {
  __shared__ float s1[64*64];
  __shared__ float s2[64*32];
  __shared__ float s3[32*8];
  __shared__ float t1[64];
  __shared__ float t2[32];
  __shared__ float t3[8];
  int t = threadIdx.x;
  for (int i = t; i < 64*64; i += 256) s1[i] = Wo1[i];
  for (int i = t; i < 64*32; i += 256) s2[i] = Wo2[i];
  if (t < 32*8) s3[t] = Wo3[t];
  if (t < 64) t1[t] = bo1[t];
  if (t < 32) t2[t] = bo2[t];
  if (t < 8)  t3[t] = bo3[t];
  __syncthreads();
  int node = blockIdx.x*256 + t;
  float f[64];
#pragma unroll
  for (int k = 0; k < 64; ++k) f[k] = F[(size_t)node*64 + k];
  float o1[64];
#pragma unroll 2
  for (int d = 0; d < 64; ++d) {
    float a = t1[d];
#pragma unroll
    for (int k = 0; k < 64; ++k) a += f[k]*s1[k*64+d];
    o1[d] = elu1(a);
  }
  float o2[32];
#pragma unroll 2
  for (int d = 0; d < 32; ++d) {
    float a = t2[d];
#pragma unroll
    for (int k = 0; k < 64; ++k) a += o1[k]*s2[k*32+d];
    o2[d] = elu1(a);
  }
#pragma unroll
  for (int d = 0; d < 8; ++d) {
    float a = t3[d];
#pragma unroll
    for (int k = 0; k < 32; ++k) a += o2[k]*s3[k*8+d];
    out[(size_t)node*8 + d] = a;
  }
  if (out_size >= NN*9) out[(size_t)NN*8 + node] = (float)batch[node];
}

extern "C" void kernel_launch(void* const* d_in, const int* in_sizes, int n_in,
                              void* d_out, int out_size, void* d_ws, size_t ws_size,
                              hipStream_t stream) {
  const float* x     = (const float*)d_in[0];
  const int*   batch = (const int*)d_in[1];
  const float* W1 = (const float*)d_in[2];
  const float* b1 = (const float*)d_in[3];
  const float* W2 = (const float*)d_in[4];
  const float* b2 = (const float*)d_in[5];
  const float* Wc[3] = {(const float*)d_in[6], (const float*)d_in[8], (const float*)d_in[10]};
  const float* bc[3] = {(const float*)d_in[7], (const float*)d_in[9], (const float*)d_in[11]};
  const float* Wo1 = (const float*)d_in[12];
  const float* bo1 = (const float*)d_in[13];
  const float* Wo2 = (const float*)d_in[14];
  const float* bo2 = (const float*)d_in[15];
  const float* Wo3 = (const float*)d_in[16];
  const float* bo3 = (const float*)d_in[17];

  float* ws = (float*)d_ws;
  float* F0 = ws;
  float* F1 = ws + (size_t)NN*64;
  float* U  = ws + (size_t)2*NN*64;
  float* V  = ws + (size_t)3*NN*64;
  float* SQ = ws + (size_t)4*NN*64;
  int*   IDX = (int*)(ws + (size_t)4*NN*64 + NN);

  k_mlp_in<<<NN/256, 256, 0, stream>>>(x, W1, b1, W2, b2, F0);
  float* cur = F0;
  float* nxt = F1;
  for (int l = 0; l < 3; ++l) {
    k_uv <<<NN/256, 256, 0, stream>>>(cur, Wc[l], bc[l], U, V, SQ);
    k_knn<<<BG*(NPG/16), 256, 0, stream>>>(cur, SQ, IDX);
    k_agg<<<(NN*64)/256, 256, 0, stream>>>(cur, U, V, IDX, nxt);
    float* tmp = cur; cur = nxt; nxt = tmp;
  }
  k_out<<<NN/256, 256, 0, stream>>>(cur, Wo1, bo1, Wo2, bo2, Wo3, bo3,
                                    batch, (float*)d_out, out_size);
}

// Round 3
// 639.856 us; speedup vs baseline: 9.4429x; 9.4429x over previous
//
#include <hip/hip_runtime.h>
#include <hip/hip_bf16.h>
#include <math.h>

#define NN   32768
#define BG   32
#define NPG  1024
#define HD   64
#define KK   24          // neighbors
#define KT   8           // k-slice tile in knn kernel

#define FLTMAX 3.402823466e38f

__device__ __forceinline__ float elu1(float x) { return x > 0.f ? x : expm1f(x); }

// ---------------- input MLP: h = elu(elu(x@W1+b1)@W2+b2) ----------------
__global__ void __launch_bounds__(256) k_mlp_in(
    const float* __restrict__ x, const float* __restrict__ W1, const float* __restrict__ b1,
    const float* __restrict__ W2, const float* __restrict__ b2, float* __restrict__ F) {
  __shared__ float sW1[8*64];
  __shared__ float sW2[64*64];
  __shared__ float sb1[64];
  __shared__ float sb2[64];
  int t = threadIdx.x;
  for (int i = t; i < 8*64; i += 256) sW1[i] = W1[i];
  for (int i = t; i < 64*64; i += 256) sW2[i] = W2[i];
  if (t < 64) { sb1[t] = b1[t]; sb2[t] = b2[t]; }
  __syncthreads();
  int node = blockIdx.x*256 + t;
  float xr[8];
#pragma unroll
  for (int i = 0; i < 8; ++i) xr[i] = x[node*8 + i];
  float h1[64];
#pragma unroll 8
  for (int k = 0; k < 64; ++k) {
    float a = sb1[k];
#pragma unroll
    for (int i = 0; i < 8; ++i) a += xr[i]*sW1[i*64+k];
    h1[k] = elu1(a);
  }
#pragma unroll 2
  for (int d = 0; d < 64; ++d) {
    float a = sb2[d];
#pragma unroll
    for (int k = 0; k < 64; ++k) a += h1[k]*sW2[k*64+d];
    F[node*64 + d] = elu1(a);
  }
}

// ---------------- per-layer: U = X@(A-B)+bc, V = X@B, SQ = rowsum(X^2) ----------------
__global__ void __launch_bounds__(256) k_uv(
    const float* __restrict__ X, const float* __restrict__ Wc, const float* __restrict__ bc,
    float* __restrict__ U, float* __restrict__ V, float* __restrict__ SQ) {
  __shared__ float sA[64*64];
  __shared__ float sB[64*64];
  __shared__ float sbc[64];
  int t = threadIdx.x;
  for (int i = t; i < 64*64; i += 256) { sA[i] = Wc[i]; sB[i] = Wc[64*64 + i]; }
  if (t < 64) sbc[t] = bc[t];
  __syncthreads();
  int node = blockIdx.x*256 + t;
  float xr[64];
  float sq = 0.f;
#pragma unroll
  for (int k = 0; k < 64; ++k) { float v = X[node*64+k]; xr[k] = v; sq += v*v; }
  SQ[node] = sq;
#pragma unroll 2
  for (int d = 0; d < 64; ++d) {
    float ua = 0.f, vb = 0.f;
#pragma unroll
    for (int k = 0; k < 64; ++k) { ua += xr[k]*sA[k*64+d]; vb += xr[k]*sB[k*64+d]; }
    U[node*64+d] = ua - vb + sbc[d];
    V[node*64+d] = vb;
  }
}

// ---------------- helpers for knn selection ----------------
// Ascending bitonic sort of 64 (value, col) pairs, one pair per lane, R rows interleaved.
// Lexicographic order: (value, col).
template<int R>
__device__ __forceinline__ void bitonic64(float (&kv)[R], int (&kc)[R], int lane) {
#pragma unroll
  for (int k = 2; k <= 64; k <<= 1) {
#pragma unroll
    for (int j = k >> 1; j > 0; j >>= 1) {
      bool keepmin = ((lane < (lane ^ j)) == ((lane & k) == 0));
#pragma unroll
      for (int r = 0; r < R; ++r) {
        float ov = __shfl_xor(kv[r], j);
        int   oc = __shfl_xor(kc[r], j);
        bool less = (ov < kv[r]) || (ov == kv[r] && oc < kc[r]);
        bool take = keepmin ? less : !less;
        if (take) { kv[r] = ov; kc[r] = oc; }
      }
    }
  }
}

// ---------------- knn: fused Gram + exact top-24 by (dist, idx) ----------------
// Block = 256 threads (4 waves), 16 rows of one graph (wave w -> rows 4w..4w+3).
// Lane l owns candidate columns {l + 64*m}, m = 0..15; distances live in registers.
// NOTE: no pointer to v[][] may escape (keeps it in VGPRs — round-2 spill lesson).
__global__ void __launch_bounds__(256) k_knn(
    const float* __restrict__ X, const float* __restrict__ SQ, int* __restrict__ IDX) {
  __shared__ float sKC[KT][NPG];               // 32 KB k-slice of all 1024 columns
  __shared__ float sRow[16][64];               // 4 KB row features
  __shared__ float sRowSq[16];
  __shared__ unsigned long long sCmp[4][4][64]; // 8 KB compacted (dist,col) per wave,row
  int g = blockIdx.x >> 6;
  int rowBase = (blockIdx.x & 63) * 16;
  int gbase = g * NPG;
  int t = threadIdx.x;
  for (int i = t; i < 16*64; i += 256)
    sRow[i>>6][i&63] = X[(size_t)(gbase + rowBase + (i>>6))*64 + (i&63)];
  if (t < 16) sRowSq[t] = SQ[gbase + rowBase + t];
  int wave = t >> 6, lane = t & 63;

  float v[4][16];
#pragma unroll
  for (int r = 0; r < 4; ++r)
#pragma unroll
    for (int m = 0; m < 16; ++m) v[r][m] = 0.f;

  for (int kt = 0; kt < 64/KT; ++kt) {
    __syncthreads();
#pragma unroll
    for (int i = 0; i < 4; ++i) {
      int c = t + 256*i;
      const float* src = X + (size_t)(gbase + c)*64 + kt*KT;
#pragma unroll
      for (int q = 0; q < KT/4; ++q) {
        float4 f4 = *reinterpret_cast<const float4*>(src + q*4);
        sKC[q*4+0][c] = f4.x; sKC[q*4+1][c] = f4.y; sKC[q*4+2][c] = f4.z; sKC[q*4+3][c] = f4.w;
      }
    }
    __syncthreads();
#pragma unroll
    for (int kk = 0; kk < KT; ++kk) {
      int k = kt*KT + kk;
      float xr0 = sRow[wave*4+0][k];
      float xr1 = sRow[wave*4+1][k];
      float xr2 = sRow[wave*4+2][k];
      float xr3 = sRow[wave*4+3][k];
#pragma unroll
      for (int m = 0; m < 16; ++m) {
        float xc = sKC[kk][lane + (m<<6)];
        v[0][m] += xr0*xc;
        v[1][m] += xr1*xc;
        v[2][m] += xr2*xc;
        v[3][m] += xr3*xc;
      }
    }
  }

  // distances: v = rsq + csq - 2*dot  (in place)
  float csq[16];
#pragma unroll
  for (int m = 0; m < 16; ++m) csq[m] = SQ[gbase + lane + (m<<6)];
#pragma unroll
  for (int r = 0; r < 4; ++r) {
    float rsq = sRowSq[wave*4 + r];
#pragma unroll
    for (int m = 0; m < 16; ++m) v[r][m] = rsq + csq[m] - 2.f*v[r][m];
  }

  // phase 2: per-lane argmin per row
  float lm[4]; int lc[4];
#pragma unroll
  for (int r = 0; r < 4; ++r) {
    float bm = v[r][0]; int bc = lane;
#pragma unroll
    for (int m = 1; m < 16; ++m) {
      float vv = v[r][m]; int cc = lane + (m<<6);
      bool b = vv < bm; bm = b ? vv : bm; bc = b ? cc : bc;
    }
    lm[r] = bm; lc[r] = bc;
  }

  // phase 3: sort lane-minima; thr = 24th smallest lane-min.
  // The 24 smallest lane-minima are 24 distinct candidates <= thr, so
  // {d <= thr} has >= 24 members and contains the exact top-24 (incl. ties).
  bitonic64<4>(lm, lc, lane);
  float thr[4];
#pragma unroll
  for (int r = 0; r < 4; ++r) thr[r] = __shfl(lm[r], 23);

  // phase 4: flag, prefix-scan, compact to LDS
  int total[4], excl[4]; unsigned fbits[4];
#pragma unroll
  for (int r = 0; r < 4; ++r) {
    unsigned bits = 0; int cnt = 0;
#pragma unroll
    for (int m = 0; m < 16; ++m) {
      bool f = v[r][m] <= thr[r];
      bits |= ((unsigned)f) << m; cnt += f;
    }
    int pre = cnt;
#pragma unroll
    for (int s = 1; s < 64; s <<= 1) { int o = __shfl_up(pre, s); if (lane >= s) pre += o; }
    total[r] = __shfl(pre, 63);
    excl[r] = pre - cnt; fbits[r] = bits;
  }
#pragma unroll
  for (int r = 0; r < 4; ++r) {
    int slot = excl[r];
#pragma unroll
    for (int m = 0; m < 16; ++m) {
      if ((fbits[r] >> m) & 1) {
        if (slot < 64)
          sCmp[wave][r][slot] =
            ((unsigned long long)__float_as_uint(v[r][m]) << 32) | (unsigned)(lane + (m<<6));
        ++slot;
      }
    }
  }
  __syncthreads();

  // phase 5/6: sort compacted candidates, emit top-24
  bool allfast = total[0] <= 64 && total[1] <= 64 && total[2] <= 64 && total[3] <= 64;
  long long ob0 = (long long)(gbase + rowBase + wave*4) * KK;
  if (allfast) {
    float sv[4]; int sc[4];
#pragma unroll
    for (int r = 0; r < 4; ++r) {
      bool in = lane < total[r];
      unsigned long long kp = in ? sCmp[wave][r][lane] : 0ull;
      sv[r] = in ? __uint_as_float((unsigned)(kp >> 32)) : FLTMAX;
      sc[r] = in ? (int)(unsigned)kp : 0x7fffffff;
    }
    bitonic64<4>(sv, sc, lane);
#pragma unroll
    for (int r = 0; r < 4; ++r)
      if (lane < KK) IDX[ob0 + (long long)r*KK + lane] = gbase + sc[r];
  } else {
    // cold exact path: 24x masked argmin extraction, fully inlined so v stays
    // in registers (r and m are compile-time constants everywhere).
#pragma unroll
    for (int r = 0; r < 4; ++r) {
      unsigned selm = 0;
      for (int it = 0; it < KK; ++it) {
        float bv = FLTMAX; int bj = 0x7fffffff;
#pragma unroll
        for (int m = 0; m < 16; ++m) {
          float vv = ((selm >> m) & 1) ? FLTMAX : v[r][m];
          int col = lane + (m << 6);
          bool b = vv < bv; bv = b ? vv : bv; bj = b ? col : bj;
        }
#pragma unroll
        for (int s = 32; s; s >>= 1) {
          float ov = __shfl_xor(bv, s); int oj = __shfl_xor(bj, s);
          bool b = (ov < bv) || (ov == bv && oj < bj);
          bv = b ? ov : bv; bj = b ? oj : bj;
        }
        if (lane == (bj & 63)) selm |= 1u << (bj >> 6);
        if (lane == 0) IDX[ob0 + (long long)r*KK + it] = gbase + bj;
      }
    }
  }
}

// ---------------- aggregate: Fn = X + elu(U + max_j V[j]) ----------------
__global__ void __launch_bounds__(256) k_agg(
    const float* __restrict__ X, const float* __restrict__ U, const float* __restrict__ V,
    const int* __restrict__ IDX, float* __restrict__ Fn) {
  int tid = blockIdx.x*256 + threadIdx.x;
  int node = tid >> 6;
  int lane = tid & 63;
  const int* idx = IDX + (size_t)node*KK;
  float m = -FLTMAX;
#pragma unroll
  for (int t = 0; t < KK; ++t) {
    int j = idx[t];                          // wave-uniform
    m = fmaxf(m, V[(size_t)j*64 + lane]);
  }
  float s = U[(size_t)node*64 + lane] + m;
  Fn[(size_t)node*64 + lane] = X[(size_t)node*64 + lane] + elu1(s);
}

// ---------------- output MLP + batch passthrough ----------------
__global__ void __launch_bounds__(256) k_out(
    const float* __restrict__ F, const float* __restrict__ Wo1, const float* __restrict__ bo1,
    const float* __restrict__ Wo2, const float* __restrict__ bo2,
    const float* __restrict__ Wo3, const float* __restrict__ bo3,
    const int* __restrict__ batch, float* __restrict__ out, int out_size) {
  __shared__ float s1[64*64];
  __shared__ float s2[64*32];
  __shared__ float s3[32*8];
  __shared__ float t1[64];
  __shared__ float t2[32];
  __shared__ float t3[8];
  int t = threadIdx.x;
  for (int i = t; i < 64*64; i += 256) s1[i] = Wo1[i];
  for (int i = t; i < 64*32; i += 256) s2[i] = Wo2[i];
  if (t < 32*8) s3[t] = Wo3[t];
  if (t < 64) t1[t] = bo1[t];
  if (t < 32) t2[t] = bo2[t];
  if (t < 8)  t3[t] = bo3[t];
  __syncthreads();
  int node = blockIdx.x*256 + t;
  float f[64];
#pragma unroll
  for (int k = 0; k < 64; ++k) f[k] = F[(size_t)node*64 + k];
  float o1[64];
#pragma unroll 2
  for (int d = 0; d < 64; ++d) {
    float a = t1[d];
#pragma unroll
    for (int k = 0; k < 64; ++k) a += f[k]*s1[k*64+d];
    o1[d] = elu1(a);
  }
  float o2[32];
#pragma unroll 2
  for (int d = 0; d < 32; ++d) {
    float a = t2[d];
#pragma unroll
    for (int k = 0; k < 64; ++k) a += o1[k]*s2[k*32+d];
    o2[d] = elu1(a);
  }
#pragma unroll
  for (int d = 0; d < 8; ++d) {
    float a = t3[d];
#pragma unroll
    for (int k = 0; k < 32; ++k) a += o2[k]*s3[k*8+d];
    out[(size_t)node*8 + d] = a;
  }
  if (out_size >= NN*9) out[(size_t)NN*8 + node] = (float)batch[node];
}

extern "C" void kernel_launch(void* const* d_in, const int* in_sizes, int n_in,
                              void* d_out, int out_size, void* d_ws, size_t ws_size,
                              hipStream_t stream) {
  const float* x     = (const float*)d_in[0];
  const int*   batch = (const int*)d_in[1];
  const float* W1 = (const float*)d_in[2];
  const float* b1 = (const float*)d_in[3];
  const float* W2 = (const float*)d_in[4];
  const float* b2 = (const float*)d_in[5];
  const float* Wc[3] = {(const float*)d_in[6], (const float*)d_in[8], (const float*)d_in[10]};
  const float* bc[3] = {(const float*)d_in[7], (const float*)d_in[9], (const float*)d_in[11]};
  const float* Wo1 = (const float*)d_in[12];
  const float* bo1 = (const float*)d_in[13];
  const float* Wo2 = (const float*)d_in[14];
  const float* bo2 = (const float*)d_in[15];
  const float* Wo3 = (const float*)d_in[16];
  const float* bo3 = (const float*)d_in[17];

  float* ws = (float*)d_ws;
  float* F0 = ws;
  float* F1 = ws + (size_t)NN*64;
  float* U  = ws + (size_t)2*NN*64;
  float* V  = ws + (size_t)3*NN*64;
  float* SQ = ws + (size_t)4*NN*64;
  int*   IDX = (int*)(ws + (size_t)4*NN*64 + NN);

  k_mlp_in<<<NN/256, 256, 0, stream>>>(x, W1, b1, W2, b2, F0);
  float* cur = F0;
  float* nxt = F1;
  for (int l = 0; l < 3; ++l) {
    k_uv <<<NN/256, 256, 0, stream>>>(cur, Wc[l], bc[l], U, V, SQ);
    k_knn<<<BG*(NPG/16), 256, 0, stream>>>(cur, SQ, IDX);
    k_agg<<<(NN*64)/256, 256, 0, stream>>>(cur, U, V, IDX, nxt);
    float* tmp = cur; cur = nxt; nxt = tmp;
  }
  k_out<<<NN/256, 256, 0, stream>>>(cur, Wo1, bo1, Wo2, bo2, Wo3, bo3,
                                    batch, (float*)d_out, out_size);
}